// Round 14
// baseline (2013.921 us; speedup 1.0000x reference)
//
#include <hip/hip_runtime.h>
#include <math.h>

#define B 64
#define S 32
#define NN 128
#define DV 512
#define DW 300
#define DH 1024
#define CLS 1024
#define T_CTRL 12
#define LL 4
#define NA 28
#define NE 16
#define MM 6

__device__ __forceinline__ float sigmoidf_(float x) { return 1.0f / (1.0f + expf(-x)); }

// ================= double-buffered 64x64-tile GEMM core (float4-k LDS) =================
template<bool TRANS, class AF, class WF>
__device__ __forceinline__ void gemm_core(int kbeg, int Kc, AF loadA, WF loadW,
                                          float* part, int Cld, int orow) {
  __shared__ float Ast[2][64 * 36];
  __shared__ float Ws[2][32 * 64];
  const int tid = threadIdx.x;
  const int j0 = blockIdx.x * 64;
  const int ntiles = Kc >> 5;
  const int rg = tid & 15, cg = tid >> 4;
  float4 av[2], wv[2];

  auto fetch = [&](int kt) {
    #pragma unroll
    for (int i2 = 0; i2 < 2; ++i2) {
      int idx = tid + i2 * 256;
      av[i2] = loadA(idx >> 3, kt + (idx & 7) * 4);
    }
    #pragma unroll
    for (int i2 = 0; i2 < 2; ++i2) {
      int idx = tid + i2 * 256;
      if (!TRANS) wv[i2] = loadW(kt + (idx >> 4), j0 + (idx & 15) * 4);
      else        wv[i2] = loadW(j0 + (idx >> 3), kt + (idx & 7) * 4);
    }
  };
  auto commit = [&](int buf) {
    #pragma unroll
    for (int i2 = 0; i2 < 2; ++i2) {
      int idx = tid + i2 * 256;
      *(float4*)&Ast[buf][(idx >> 3) * 36 + (idx & 7) * 4] = av[i2];
    }
    #pragma unroll
    for (int i2 = 0; i2 < 2; ++i2) {
      int idx = tid + i2 * 256;
      if (!TRANS) {
        *(float4*)&Ws[buf][(idx >> 4) * 64 + (idx & 15) * 4] = wv[i2];
      } else {
        int jloc = idx >> 3, k4 = (idx & 7) * 4;
        Ws[buf][(k4 + 0) * 64 + jloc] = wv[i2].x;
        Ws[buf][(k4 + 1) * 64 + jloc] = wv[i2].y;
        Ws[buf][(k4 + 2) * 64 + jloc] = wv[i2].z;
        Ws[buf][(k4 + 3) * 64 + jloc] = wv[i2].w;
      }
    }
  };

  float acc[4][4] = {};
  fetch(kbeg);
  commit(0);
  __syncthreads();
  for (int i = 0; i < ntiles; ++i) {
    if (i + 1 < ntiles) fetch(kbeg + (i + 1) * 32);
    const float* As = &Ast[i & 1][0];
    const float* Wp = &Ws[i & 1][0];
    #pragma unroll
    for (int kq = 0; kq < 8; ++kq) {
      float4 a0 = *(const float4*)&As[(rg     ) * 36 + kq * 4];
      float4 a1 = *(const float4*)&As[(rg + 16) * 36 + kq * 4];
      float4 a2 = *(const float4*)&As[(rg + 32) * 36 + kq * 4];
      float4 a3 = *(const float4*)&As[(rg + 48) * 36 + kq * 4];
      float4 w0 = *(const float4*)&Wp[(kq * 4 + 0) * 64 + cg * 4];
      float4 w1 = *(const float4*)&Wp[(kq * 4 + 1) * 64 + cg * 4];
      float4 w2 = *(const float4*)&Wp[(kq * 4 + 2) * 64 + cg * 4];
      float4 w3 = *(const float4*)&Wp[(kq * 4 + 3) * 64 + cg * 4];
      #define STEP(m, AV) \
        acc[m][0]=fmaf(AV.x,w0.x,acc[m][0]); acc[m][1]=fmaf(AV.x,w0.y,acc[m][1]); \
        acc[m][2]=fmaf(AV.x,w0.z,acc[m][2]); acc[m][3]=fmaf(AV.x,w0.w,acc[m][3]); \
        acc[m][0]=fmaf(AV.y,w1.x,acc[m][0]); acc[m][1]=fmaf(AV.y,w1.y,acc[m][1]); \
        acc[m][2]=fmaf(AV.y,w1.z,acc[m][2]); acc[m][3]=fmaf(AV.y,w1.w,acc[m][3]); \
        acc[m][0]=fmaf(AV.z,w2.x,acc[m][0]); acc[m][1]=fmaf(AV.z,w2.y,acc[m][1]); \
        acc[m][2]=fmaf(AV.z,w2.z,acc[m][2]); acc[m][3]=fmaf(AV.z,w2.w,acc[m][3]); \
        acc[m][0]=fmaf(AV.w,w3.x,acc[m][0]); acc[m][1]=fmaf(AV.w,w3.y,acc[m][1]); \
        acc[m][2]=fmaf(AV.w,w3.z,acc[m][2]); acc[m][3]=fmaf(AV.w,w3.w,acc[m][3]);
      STEP(0, a0) STEP(1, a1) STEP(2, a2) STEP(3, a3)
      #undef STEP
    }
    if (i + 1 < ntiles) { __syncthreads(); commit((i + 1) & 1); __syncthreads(); }
  }
  float* op = part + (size_t)orow * 64 * Cld + j0 + cg * 4;
  #pragma unroll
  for (int m = 0; m < 4; ++m)
    *(float4*)&op[(size_t)(rg + 16 * m) * Cld] = make_float4(acc[m][0], acc[m][1], acc[m][2], acc[m][3]);
}

// ---------------- init (also zeroes split-K counters) ----------------
__global__ void init_kernel(float* c_lstm, float* c_ctrl, float* att_stack, float* mem, float* sptr,
                            int* cnt) {
  int idx = blockIdx.x * 256 + threadIdx.x;
  if (idx < B * DH) { c_lstm[idx] = 0.f; c_ctrl[idx] = 0.f; }
  if (idx < B * NN * LL) att_stack[idx] = 0.f;
  if (idx < B * DV) mem[idx] = 0.f;
  if (idx < B * LL) sptr[idx] = ((idx & (LL - 1)) == 0) ? 1.f : 0.f;
  if (idx < 1024) cnt[idx] = 0;
}

// ---------------- embq: rows t*B+b, padded 300->320 ----------------
__global__ void embq_kernel(const int* __restrict__ questions, const float* __restrict__ enc_emb,
                            float* __restrict__ embq) {
  int row = blockIdx.x;
  int t = row >> 6, b = row & 63;
  int qid = questions[b * S + t];
  int c = threadIdx.x;
  embq[(size_t)row * 320 + c] = (c < DW) ? enc_emb[(size_t)qid * DW + c] : 0.f;
}

// ---------------- X = embq @ Wx for all steps (rows 2048) ----------------
__global__ __launch_bounds__(256) void xgemm_kernel(const float* __restrict__ embq,
                                                    const float* __restrict__ Wx,
                                                    float* __restrict__ X) {
  auto Al = [&](int r, int k) -> float4 {
    return *(const float4*)&embq[(size_t)(blockIdx.y * 64 + r) * 320 + k];
  };
  auto Wl = [&](int k, int j) -> float4 {
    if (k < 300) return *(const float4*)&Wx[(size_t)k * 4096 + j];
    return make_float4(0.f, 0.f, 0.f, 0.f);
  };
  gemm_core<false>(0, 320, Al, Wl, X, 4096, blockIdx.y);
}

// ---------------- F2 = attr_emb @ W_find (rows padded to 1024) ----------------
__global__ __launch_bounds__(256) void f2_kernel(const float* __restrict__ attr_emb,
                                                 const float* __restrict__ W_find,
                                                 float* __restrict__ F2) {
  auto Al = [&](int r, int k) -> float4 {
    int gr = blockIdx.y * 64 + r;
    if (gr > 999) gr = 999;
    return *(const float4*)&attr_emb[(size_t)gr * 512 + k];
  };
  auto Wl = [&](int k, int j) -> float4 { return *(const float4*)&W_find[(size_t)k * 512 + j]; };
  gemm_core<false>(0, 512, Al, Wl, F2, 512, blockIdx.y);
}

// ---------------- LSTM fused step: h_{t-1}@Wh partials + deterministic tail gate ----------------
// grid (64, 8). Column-group g = blockIdx.x & 15 (gate cols [64g,64g+64)); its 32 producer
// blocks (tiles g,g+16,g+32,g+48 x 8 chunks) bump 4 quadrant counters; last arrival per
// (g,quadrant) computes the gate for (16 b-rows x 64 j-cols). Fixed c-order => deterministic.
__global__ __launch_bounds__(256) void lstm_step_kernel(const float* __restrict__ h_prev,
                                                        const float* __restrict__ Wh,
                                                        float* __restrict__ part,
                                                        const float* __restrict__ X, int t,
                                                        const float* __restrict__ b_lstm,
                                                        float* __restrict__ h_out,
                                                        float* __restrict__ c_st,
                                                        int* __restrict__ cnt) {
  auto Al = [&](int r, int k) -> float4 { return *(const float4*)&h_prev[(size_t)r * 1024 + k]; };
  auto Wl = [&](int k, int j) -> float4 { return *(const float4*)&Wh[(size_t)k * 4096 + j]; };
  gemm_core<false>(blockIdx.y * 128, 128, Al, Wl, part, 4096, blockIdx.y);

  __shared__ int sel[4];
  const int tid = threadIdx.x;
  const int g = blockIdx.x & 15;
  __syncthreads();                       // all gemm stores issued (vmcnt drained at barrier)
  if (tid < 4) {
    __builtin_amdgcn_fence(__ATOMIC_RELEASE, "agent");   // write back this XCD's L2
    int old = atomicAdd(&cnt[(g * 4 + tid) * 16], 1);
    sel[tid] = (old == 32 * t - 1) ? 1 : 0;
  }
  __syncthreads();
  if (sel[0] | sel[1] | sel[2] | sel[3]) {
    if (tid == 0) __builtin_amdgcn_fence(__ATOMIC_ACQUIRE, "agent");  // invalidate caches
    __syncthreads();
    #pragma unroll
    for (int q = 0; q < 4; ++q) {
      if (!sel[q]) continue;
      int b = q * 16 + (tid >> 4);
      int j = g * 64 + (tid & 15) * 4;
      const float* xr = X + ((size_t)t * 64 + b) * 4096;
      float4 gi = *(const float4*)&xr[j];
      float4 gf = *(const float4*)&xr[1024 + j];
      float4 gg = *(const float4*)&xr[2048 + j];
      float4 go = *(const float4*)&xr[3072 + j];
      for (int c = 0; c < 8; ++c) {
        const float* p = part + (size_t)c * 262144 + b * 4096;
        float4 v;
        v = *(const float4*)&p[j];        gi.x += v.x; gi.y += v.y; gi.z += v.z; gi.w += v.w;
        v = *(const float4*)&p[1024 + j]; gf.x += v.x; gf.y += v.y; gf.z += v.z; gf.w += v.w;
        v = *(const float4*)&p[2048 + j]; gg.x += v.x; gg.y += v.y; gg.z += v.z; gg.w += v.w;
        v = *(const float4*)&p[3072 + j]; go.x += v.x; go.y += v.y; go.z += v.z; go.w += v.w;
      }
      float4 bi = *(const float4*)&b_lstm[j];
      float4 bf = *(const float4*)&b_lstm[1024 + j];
      float4 bg = *(const float4*)&b_lstm[2048 + j];
      float4 bo = *(const float4*)&b_lstm[3072 + j];
      gi.x += bi.x; gi.y += bi.y; gi.z += bi.z; gi.w += bi.w;
      gf.x += bf.x; gf.y += bf.y; gf.z += bf.z; gf.w += bf.w;
      gg.x += bg.x; gg.y += bg.y; gg.z += bg.z; gg.w += bg.w;
      go.x += bo.x; go.y += bo.y; go.z += bo.z; go.w += bo.w;
      int idx = b * 1024 + j;
      float4 cv = *(const float4*)&c_st[idx];
      float4 cn, hn;
      cn.x = sigmoidf_(gf.x) * cv.x + sigmoidf_(gi.x) * tanhf(gg.x);
      cn.y = sigmoidf_(gf.y) * cv.y + sigmoidf_(gi.y) * tanhf(gg.y);
      cn.z = sigmoidf_(gf.z) * cv.z + sigmoidf_(gi.z) * tanhf(gg.z);
      cn.w = sigmoidf_(gf.w) * cv.w + sigmoidf_(gi.w) * tanhf(gg.w);
      hn.x = sigmoidf_(go.x) * tanhf(cn.x);
      hn.y = sigmoidf_(go.y) * tanhf(cn.y);
      hn.z = sigmoidf_(go.z) * tanhf(cn.z);
      hn.w = sigmoidf_(go.w) * tanhf(cn.w);
      *(float4*)&c_st[idx] = cn;
      *(float4*)&h_out[idx] = hn;
    }
  }
}

// ---------------- LSTM gate (t=0 only): h = gate(X_0) ----------------
__global__ __launch_bounds__(256) void lstm_gate0_kernel(const float* __restrict__ X,
                                                         const float* __restrict__ b_lstm,
                                                         float* __restrict__ h_out,
                                                         float* __restrict__ c_st) {
  int idx = blockIdx.x * 256 + threadIdx.x;
  int b = idx >> 10, j = idx & 1023;
  const float* xr = X + (size_t)b * 4096;
  float gi = xr[j] + b_lstm[j];
  float gf = xr[1024 + j] + b_lstm[1024 + j];
  float gg = xr[2048 + j] + b_lstm[2048 + j];
  float go = xr[3072 + j] + b_lstm[3072 + j];
  float c = sigmoidf_(gi) * tanhf(gg);   // c_prev = 0
  h_out[idx] = sigmoidf_(go) * tanhf(c);
  c_st[idx] = c;
}

// ---------------- C1: cq partials (+ fused mem-EPI of previous iter) ----------------
__global__ __launch_bounds__(256) void c1_kernel(const float* __restrict__ c_ctrl,
                                                 const float* __restrict__ outs, const int* __restrict__ qlen,
                                                 const float* __restrict__ W_cq, float* __restrict__ partA,
                                                 const float* __restrict__ partE, const float* __restrict__ mp,
                                                 float* __restrict__ mem, int do_epi) {
  if (blockIdx.x == 16) {
    if (!do_epi) return;
    int t0 = blockIdx.y * 256 + threadIdx.x;
    #pragma unroll
    for (int i = 0; i < 4; ++i) {
      int f4 = t0 + i * 2048;
      int b = f4 >> 7, j = (f4 & 127) * 4;
      const float* m = &mp[b * 6];
      float s04 = m[0] + m[1] + m[2] + m[3] + m[4];
      float4 s = make_float4(0.f, 0.f, 0.f, 0.f);
      for (int c = 0; c < 8; ++c) {
        float4 v = *(const float4*)&partE[(size_t)c * 32768 + b * 512 + j];
        s.x += v.x; s.y += v.y; s.z += v.z; s.w += v.w;
      }
      float4 o = *(const float4*)&mem[b * 512 + j];
      o.x = s04 * o.x + m[5] * s.x; o.y = s04 * o.y + m[5] * s.y;
      o.z = s04 * o.z + m[5] * s.z; o.w = s04 * o.w + m[5] * s.w;
      *(float4*)&mem[b * 512 + j] = o;
    }
    return;
  }
  auto Al = [&](int r, int k) -> float4 {
    if (k < 1024) return *(const float4*)&c_ctrl[r * 1024 + k];
    int tq = qlen[r] - 1;
    return *(const float4*)&outs[(size_t)tq * 65536 + r * 1024 + (k - 1024)];
  };
  auto Wl = [&](int k, int j) -> float4 { return *(const float4*)&W_cq[(size_t)k * 1024 + j]; };
  gemm_core<false>(blockIdx.y * 256, 256, Al, Wl, partA, 1024, blockIdx.y);
}

// ---------------- C2: am partials, A = tanh(reduce(partA)+b_cq) ----------------
__global__ __launch_bounds__(256) void c2_kernel(const float* __restrict__ partA,
                                                 const float* __restrict__ b_cq,
                                                 const float* __restrict__ W_att,
                                                 const float* __restrict__ W_mod,
                                                 float* __restrict__ partB) {
  auto Al = [&](int r, int k) -> float4 {
    float4 s = *(const float4*)&b_cq[k];
    for (int c = 0; c < 8; ++c) {
      float4 v = *(const float4*)&partA[(size_t)c * 65536 + r * 1024 + k];
      s.x += v.x; s.y += v.y; s.z += v.z; s.w += v.w;
    }
    return make_float4(tanhf(s.x), tanhf(s.y), tanhf(s.z), tanhf(s.w));
  };
  auto Wl = [&](int k, int j) -> float4 {
    if (j < 1024) return *(const float4*)&W_att[(size_t)k * 1024 + j];
    float v[4];
    #pragma unroll
    for (int i = 0; i < 4; ++i) {
      int jj = j + i;
      v[i] = (jj < 1030) ? W_mod[(size_t)k * 6 + (jj - 1024)] : 0.f;
    }
    return make_float4(v[0], v[1], v[2], v[3]);
  };
  gemm_core<false>(blockIdx.y * 64, 64, Al, Wl, partB, 1088, blockIdx.y);
}

// ---------------- attn: aw-reduce + al + softmax + c_ctrl (merged) ----------------
__global__ __launch_bounds__(256) void attn_kernel(const float* __restrict__ partB,
                                                   const float* __restrict__ outs,
                                                   const int* __restrict__ qlen,
                                                   float* __restrict__ c_ctrl) {
  int b = blockIdx.x >> 2, hq = blockIdx.x & 3;
  int tid = threadIdx.x;
  __shared__ float aw[DH];
  __shared__ float alv[S];
  __shared__ float cvs[S];
  {
    int c4 = tid * 4;
    float4 s = make_float4(0.f, 0.f, 0.f, 0.f);
    for (int c = 0; c < 16; ++c) {
      float4 v = *(const float4*)&partB[(size_t)c * 69632 + b * 1088 + c4];
      s.x += v.x; s.y += v.y; s.z += v.z; s.w += v.w;
    }
    *(float4*)&aw[c4] = s;
  }
  __syncthreads();
  {
    int wv = tid >> 6, lane = tid & 63;
    #pragma unroll
    for (int u = 0; u < 4; ++u) {
      int s2 = wv * 4 + u;
      const float4* orow = (const float4*)&outs[(size_t)s2 * 65536 + b * 1024];
      float pr = 0.f;
      #pragma unroll
      for (int q = 0; q < 4; ++q) {
        float4 f = orow[lane + 64 * q];
        float4 w = *(const float4*)&aw[(lane + 64 * q) * 4];
        pr += f.x * w.x + f.y * w.y + f.z * w.z + f.w * w.w;
      }
      #pragma unroll
      for (int off = 32; off > 0; off >>= 1) pr += __shfl_xor(pr, off);
      if (lane == 0) alv[s2] = pr;
    }
  }
  __syncthreads();
  if (tid < 64) {
    int len = qlen[b];
    float v = (tid < S && tid < len) ? alv[tid] : -1e9f;
    float mx = v;
    #pragma unroll
    for (int off = 32; off > 0; off >>= 1) mx = fmaxf(mx, __shfl_xor(mx, off));
    float e = (tid < S && tid < len) ? expf(v - mx) : 0.f;
    float sm = e;
    #pragma unroll
    for (int off = 32; off > 0; off >>= 1) sm += __shfl_xor(sm, off);
    if (tid < S) cvs[tid] = e / sm;
  }
  __syncthreads();
  {
    int h = hq * 256 + tid;
    float a = 0.f;
    #pragma unroll 8
    for (int s2 = 0; s2 < S; ++s2)
      a = fmaf(cvs[s2], outs[(size_t)s2 * 65536 + b * 1024 + h], a);
    c_ctrl[b * 1024 + h] = a;
  }
}

// ---------------- C4: c_i partials ----------------
__global__ __launch_bounds__(256) void c4_kernel(const float* __restrict__ c_ctrl,
                                                 const float* __restrict__ W_q,
                                                 float* __restrict__ partC) {
  auto Al = [&](int r, int k) -> float4 { return *(const float4*)&c_ctrl[r * 1024 + k]; };
  auto Wl = [&](int k, int j) -> float4 { return *(const float4*)&W_q[(size_t)k * 512 + j]; };
  gemm_core<false>(blockIdx.y * 64, 64, Al, Wl, partC, 512, blockIdx.y);
}

// ---------------- prep: c_i reduce(+relu) + we logits + softmaxes + ptrs + a_in/a_w4/asum ----------------
__global__ __launch_bounds__(256) void prep_kernel(const float* __restrict__ partC,
                                                   const float* __restrict__ partB,
                                                   const float* __restrict__ b_q,
                                                   const float* __restrict__ edge_cat,
                                                   const float* __restrict__ sptr_in,
                                                   const float* __restrict__ att_stack,
                                                   float* __restrict__ c_i, float* __restrict__ we,
                                                   float* __restrict__ mp, float* __restrict__ spv,
                                                   float* __restrict__ ain, float* __restrict__ aw4,
                                                   float* __restrict__ asum) {
  int b = blockIdx.x, tid = threadIdx.x;
  __shared__ float ci[512];
  __shared__ float lds[64];
  for (int col = tid; col < 512; col += 256) {
    float s = b_q[col];
    for (int c = 0; c < 16; ++c) s += partC[(size_t)c * 32768 + b * 512 + col];
    s = fmaxf(s, 0.f);
    ci[col] = s;
    c_i[b * 512 + col] = s;
  }
  if (tid < MM) {
    float s = 0.f;
    for (int c = 0; c < 16; ++c) s += partB[(size_t)c * 69632 + b * 1088 + 1024 + tid];
    lds[16 + tid] = s;
  }
  __syncthreads();
  {
    int wv = tid >> 6, lane = tid & 63;
    for (int e = wv; e < NE; e += 4) {
      const float* er = &edge_cat[(size_t)e * 512];
      float p = 0.f;
      #pragma unroll
      for (int q = 0; q < 8; ++q) p = fmaf(ci[lane + 64 * q], er[lane + 64 * q], p);
      #pragma unroll
      for (int off = 32; off > 0; off >>= 1) p += __shfl_xor(p, off);
      if (lane == 0) lds[e] = p;
    }
  }
  __syncthreads();
  if (tid == 0) {
    float mx = lds[0];
    for (int e = 1; e < NE; ++e) mx = fmaxf(mx, lds[e]);
    float sm = 0.f, ex[NE];
    for (int e = 0; e < NE; ++e) { ex[e] = expf(lds[e] - mx); sm += ex[e]; }
    for (int e = 0; e < NE; ++e) we[b * NE + e] = ex[e] / sm;
    float mx2 = lds[16];
    for (int m = 1; m < MM; ++m) mx2 = fmaxf(mx2, lds[16 + m]);
    float e6[MM], sm2 = 0.f;
    for (int m = 0; m < MM; ++m) { e6[m] = expf(lds[16 + m] - mx2); sm2 += e6[m]; }
    float p0 = sptr_in[b * 4 + 0], p1 = sptr_in[b * 4 + 1];
    float p2 = sptr_in[b * 4 + 2], p3 = sptr_in[b * 4 + 3];
    float sp[12];
    sp[0] = p0; sp[1] = p1; sp[2] = p2; sp[3] = p3;
    sp[4] = 0.f;      sp[5] = p0; sp[6] = p1; sp[7] = p2 + p3;
    sp[8] = p0 + p1;  sp[9] = p2; sp[10] = p3; sp[11] = 0.f;
    for (int i = 0; i < 12; ++i) { spv[b * 12 + i] = sp[i]; lds[22 + i] = sp[i]; }
    float val[MM];
    val[0] = rintf(p0 + p1 + p2 + p3);
    val[1] = rintf(p0 + p1 + p2);
    val[2] = rintf(p1 + p2 + p3);
    val[3] = val[2];
    val[4] = rintf(p2 + p3);
    val[5] = val[2];
    float mpv[MM], ssum = 0.f;
    #pragma unroll
    for (int m = 0; m < MM; ++m) { mpv[m] = (e6[m] / sm2) * val[m]; ssum += mpv[m]; }
    float inv = (ssum > 0.f) ? 1.f / ssum : 1.f;
    #pragma unroll
    for (int m = 0; m < MM; ++m) mp[b * MM + m] = mpv[m] * inv;
  }
  __syncthreads();
  if (tid < 128) {
    float4 st = *(const float4*)&att_stack[(b * NN + tid) * LL];
    float ainv = st.x * lds[22] + st.y * lds[23] + st.z * lds[24] + st.w * lds[25];
    float ap   = st.x * lds[30] + st.y * lds[31] + st.z * lds[32] + st.w * lds[33];
    ain[b * NN + tid] = ainv;
    aw4[b * NN + tid] = fminf(ap, ainv);
    float t2 = ainv;
    #pragma unroll
    for (int off = 32; off > 0; off >>= 1) t2 += __shfl_xor(t2, off);
    if ((tid & 63) == 0) lds[40 + (tid >> 6)] = t2;
  }
  __syncthreads();
  if (tid == 0) asum[b] = lds[40] + lds[41] + 1e-6f;
}

// ---------------- stackf: afind (via F2·c_i) + atrans + pooled ----------------
__global__ __launch_bounds__(256) void stackf_kernel(const int* __restrict__ v_idx,
                                                     const float* __restrict__ attr_emb,
                                                     const float* __restrict__ F2,
                                                     const float* __restrict__ c_i,
                                                     const float* __restrict__ we,
                                                     const int* __restrict__ cat_mat,
                                                     const float* __restrict__ conn,
                                                     const float* __restrict__ ain,
                                                     const float* __restrict__ asum,
                                                     float* __restrict__ afind,
                                                     float* __restrict__ atr,
                                                     float* __restrict__ pooled) {
  int job = blockIdx.x, tid = threadIdx.x;
  __shared__ float lds[192];
  if (job < 2048) {
    int gw = job * 4 + (tid >> 6);
    int b = gw >> 7, n = gw & 127, lane = tid & 63;
    int vid = v_idx[b * NN + n];
    const float4* fp = (const float4*)&F2[(size_t)vid * DV];
    const float4* up = (const float4*)&c_i[(size_t)b * DV];
    float pr = 0.f;
    #pragma unroll
    for (int q = 0; q < 2; ++q) {
      float4 f = fp[lane + 64 * q], u = up[lane + 64 * q];
      pr += f.x * u.x + f.y * u.y + f.z * u.z + f.w * u.w;
    }
    #pragma unroll
    for (int off = 32; off > 0; off >>= 1) pr += __shfl_xor(pr, off);
    if (lane == 0) afind[b * NN + n] = sigmoidf_(pr * 0.04419417382415922f);
  } else if (job < 2560) {
    int j2 = job - 2048;
    int b = j2 >> 3, ig = j2 & 7;
    if (tid < 128) lds[tid] = ain[b * NN + tid];
    else if (tid < 144) lds[tid] = we[b * NE + tid - 128];
    __syncthreads();
    int i = ig * 16 + (tid >> 4);
    const int* crow = &cat_mat[((size_t)b * NN + i) * NN];
    const float* nrow = &conn[((size_t)b * NN + i) * NN];
    float a = 0.f;
    #pragma unroll
    for (int q = 0; q < 8; ++q) {
      int j = (tid & 15) + 16 * q;
      a = fmaf(lds[128 + crow[j]] * nrow[j], lds[j], a);
    }
    a += __shfl_xor(a, 1); a += __shfl_xor(a, 2); a += __shfl_xor(a, 4); a += __shfl_xor(a, 8);
    if ((tid & 15) == 0) atr[b * NN + i] = fminf(a, 1.f);
  } else {
    int j3 = job - 2560;
    int b = j3 >> 1, d = (j3 & 1) * 256 + tid;
    int* vidL = (int*)&lds[128];
    if (tid < 128) { lds[tid] = ain[b * NN + tid]; vidL[tid] = v_idx[b * NN + tid]; }
    __syncthreads();
    float a = 0.f;
    #pragma unroll 4
    for (int n = 0; n < NN; ++n)
      a = fmaf(lds[n], attr_emb[(size_t)vidL[n] * DV + d], a);
    pooled[b * DV + d] = a / asum[b];
  }
}

// ---------------- C7 + update (merged): grid (8,16) ----------------
__global__ __launch_bounds__(256) void c7u_kernel(const float* __restrict__ pooled,
                                                  const float* __restrict__ W_desc,
                                                  float* __restrict__ partE,
                                                  const float* __restrict__ spv,
                                                  const float* __restrict__ mp,
                                                  const float* __restrict__ afind,
                                                  const float* __restrict__ ain,
                                                  const float* __restrict__ atr,
                                                  const float* __restrict__ aw4,
                                                  float* __restrict__ att_stack,
                                                  float* __restrict__ sptr) {
  int tid = threadIdx.x;
  if (blockIdx.y < 8) {
    auto Al = [&](int r, int k) -> float4 { return *(const float4*)&pooled[r * 512 + k]; };
    auto Wl = [&](int k, int j) -> float4 { return *(const float4*)&W_desc[(size_t)k * 512 + j]; };
    gemm_core<false>(blockIdx.y * 64, 64, Al, Wl, partE, 512, blockIdx.y);
    return;
  }
  int b = (blockIdx.y - 8) * 8 + blockIdx.x;
  __shared__ float sp[12], smp[MM];
  if (tid < 12) sp[tid] = spv[b * 12 + tid];
  else if (tid < 12 + MM) smp[tid - 12] = mp[b * MM + (tid - 12)];
  __syncthreads();
  #pragma unroll
  for (int i = 0; i < 2; ++i) {
    int e = tid + i * 256;
    int n = e >> 2, l = e & 3;
    float st = att_stack[(b * NN + n) * LL + l];
    float keep = smp[0] + smp[5] + smp[1] * (1.f - sp[4 + l]) + (smp[2] + smp[3]) * (1.f - sp[l])
               + smp[4] * (1.f - sp[8 + l]);
    float add = sp[4 + l] * smp[1] * afind[b * NN + n]
              + sp[l] * (smp[2] * atr[b * NN + n] + smp[3] * ain[b * NN + n] * afind[b * NN + n])
              + sp[8 + l] * smp[4] * aw4[b * NN + n];
    att_stack[(b * NN + n) * LL + l] = keep * st + add;
  }
  if (tid < LL)
    sptr[b * LL + tid] = (smp[0] + smp[2] + smp[3]) * sp[tid] + smp[1] * sp[4 + tid]
                       + (smp[4] + smp[5]) * sp[8 + tid];
}

// ---------------- CL1: h1 partials; A = [EPI(mem,partE) | outs@qlen] ----------------
__global__ __launch_bounds__(256) void cl1_kernel(const float* __restrict__ partE,
                                                  const float* __restrict__ mp,
                                                  const float* __restrict__ mem,
                                                  const float* __restrict__ outs,
                                                  const int* __restrict__ qlen,
                                                  const float* __restrict__ W_cls1,
                                                  float* __restrict__ partH) {
  auto Al = [&](int r, int k) -> float4 {
    if (k < 512) {
      float4 s = make_float4(0.f, 0.f, 0.f, 0.f);
      for (int c = 0; c < 8; ++c) {
        float4 v = *(const float4*)&partE[(size_t)c * 32768 + r * 512 + k];
        s.x += v.x; s.y += v.y; s.z += v.z; s.w += v.w;
      }
      const float* m = &mp[r * 6];
      float s04 = m[0] + m[1] + m[2] + m[3] + m[4];
      float4 o = *(const float4*)&mem[r * 512 + k];
      return make_float4(s04 * o.x + m[5] * s.x, s04 * o.y + m[5] * s.y,
                         s04 * o.z + m[5] * s.z, s04 * o.w + m[5] * s.w);
    }
    int tq = qlen[r] - 1;
    return *(const float4*)&outs[(size_t)tq * 65536 + r * 1024 + (k - 512)];
  };
  auto Wl = [&](int k, int j) -> float4 { return *(const float4*)&W_cls1[(size_t)k * 1024 + j]; };
  gemm_core<false>(blockIdx.y * 192, 192, Al, Wl, partH, 1024, blockIdx.y);
}

// ---------------- CL2: logits partials; A = relu(reduce(partH)+b_cls1) ----------------
__global__ __launch_bounds__(256) void cl2_kernel(const float* __restrict__ partH,
                                                  const float* __restrict__ b_cls1,
                                                  const float* __restrict__ W_cls2,
                                                  float* __restrict__ partJ) {
  auto Al = [&](int r, int k) -> float4 {
    float4 s = *(const float4*)&b_cls1[k];
    for (int c = 0; c < 8; ++c) {
      float4 v = *(const float4*)&partH[(size_t)c * 65536 + r * 1024 + k];
      s.x += v.x; s.y += v.y; s.z += v.z; s.w += v.w;
    }
    return make_float4(fmaxf(s.x, 0.f), fmaxf(s.y, 0.f), fmaxf(s.z, 0.f), fmaxf(s.w, 0.f));
  };
  auto Wl = [&](int k, int j) -> float4 {
    float v[4];
    #pragma unroll
    for (int i = 0; i < 4; ++i) { int jj = j + i; v[i] = (jj < NA) ? W_cls2[(size_t)k * NA + jj] : 0.f; }
    return make_float4(v[0], v[1], v[2], v[3]);
  };
  gemm_core<false>(blockIdx.y * 128, 128, Al, Wl, partJ, 64, blockIdx.y);
}

// ---------------- CL3: final logits reduce ----------------
__global__ void cl3_kernel(const float* __restrict__ partJ, const float* __restrict__ b_cls2,
                           float* __restrict__ logits) {
  int idx = blockIdx.x * 256 + threadIdx.x;
  if (idx >= B * NA) return;
  int r = idx / NA, j = idx - r * NA;
  float s = b_cls2[j];
  for (int c = 0; c < 8; ++c) s += partJ[(size_t)c * 4096 + r * 64 + j];
  logits[idx] = s;
}

extern "C" void kernel_launch(void* const* d_in, const int* in_sizes, int n_in,
                              void* d_out, int out_size, void* d_ws, size_t ws_size,
                              hipStream_t stream) {
  const int*   questions = (const int*)d_in[0];
  const int*   qlen      = (const int*)d_in[1];
  const float* conn      = (const float*)d_in[2];
  const int*   cat_mat   = (const int*)d_in[3];
  const int*   v_idx     = (const int*)d_in[4];
  const float* attr_emb  = (const float*)d_in[5];
  const float* edge_cat  = (const float*)d_in[6];
  const float* enc_emb   = (const float*)d_in[7];
  const float* Wx        = (const float*)d_in[8];
  const float* Wh        = (const float*)d_in[9];
  const float* b_lstm    = (const float*)d_in[10];
  const float* W_cq      = (const float*)d_in[11];
  const float* b_cq      = (const float*)d_in[12];
  const float* W_mod     = (const float*)d_in[13];
  const float* W_att     = (const float*)d_in[14];
  const float* W_q       = (const float*)d_in[15];
  const float* b_q       = (const float*)d_in[16];
  const float* W_find    = (const float*)d_in[17];
  const float* W_desc    = (const float*)d_in[18];
  const float* W_cls1    = (const float*)d_in[19];
  const float* b_cls1    = (const float*)d_in[20];
  const float* W_cls2    = (const float*)d_in[21];
  const float* b_cls2    = (const float*)d_in[22];
  float* logits = (float*)d_out;

  float* w = (float*)d_ws;
  size_t off = 0;
  float* outs      = w + off; off += (size_t)S * B * DH;     // 2,097,152
  float* embq      = w + off; off += (size_t)S * B * 320;    //   655,360
  float* X         = w + off; off += (size_t)S * B * 4096;   // 8,388,608
  float* F2        = w + off; off += 1024 * 512;             //   524,288
  float* share     = w + off; off += 2457600;                // partLSTM / partA / partB / partC union
  float* partE     = w + off; off += 262144;
  float* partH     = w + off; off += 524288;
  float* partJ     = w + off; off += 32768;
  float* c_ctrl    = w + off; off += B * DH;
  float* c_lstm    = w + off; off += B * DH;
  float* ci_buf    = w + off; off += B * DV;
  float* we_buf    = w + off; off += B * NE;
  float* mp_buf    = w + off; off += B * MM;
  float* spv_buf   = w + off; off += B * 12;
  float* ain_buf   = w + off; off += B * NN;
  float* aw4_buf   = w + off; off += B * NN;
  float* afind_buf = w + off; off += B * NN;
  float* atr_buf   = w + off; off += B * NN;
  float* asum_buf  = w + off; off += B;
  float* att_stack = w + off; off += B * NN * LL;
  float* sptr_buf  = w + off; off += B * LL;
  float* mem       = w + off; off += B * DV;
  float* pooled    = w + off; off += B * DV;
  int*   cnt       = (int*)(w + off); off += 1024;

  float* partLSTM = share;
  float* partA = share;
  float* partB = share + 524288;
  float* partC = share + 1638400;

  init_kernel<<<256, 256, 0, stream>>>(c_lstm, c_ctrl, att_stack, mem, sptr_buf, cnt);
  embq_kernel<<<S * B, 320, 0, stream>>>(questions, enc_emb, embq);
  xgemm_kernel<<<dim3(64, 32), 256, 0, stream>>>(embq, Wx, X);
  f2_kernel<<<dim3(8, 16), 256, 0, stream>>>(attr_emb, W_find, F2);

  // t = 0: h = gate(X_0) (no h-GEMM)
  lstm_gate0_kernel<<<(B * DH) / 256, 256, 0, stream>>>(X, b_lstm, outs, c_lstm);
  for (int t = 1; t < S; ++t) {
    lstm_step_kernel<<<dim3(64, 8), 256, 0, stream>>>(outs + (size_t)(t - 1) * B * DH, Wh,
                                                      partLSTM, X, t, b_lstm,
                                                      outs + (size_t)t * B * DH, c_lstm, cnt);
  }

  for (int it = 0; it < T_CTRL; ++it) {
    c1_kernel<<<dim3(17, 8), 256, 0, stream>>>(c_ctrl, outs, qlen, W_cq, partA,
                                               partE, mp_buf, mem, it > 0 ? 1 : 0);
    c2_kernel<<<dim3(17, 16), 256, 0, stream>>>(partA, b_cq, W_att, W_mod, partB);
    attn_kernel<<<256, 256, 0, stream>>>(partB, outs, qlen, c_ctrl);
    c4_kernel<<<dim3(8, 16), 256, 0, stream>>>(c_ctrl, W_q, partC);
    prep_kernel<<<64, 256, 0, stream>>>(partC, partB, b_q, edge_cat, sptr_buf, att_stack,
                                        ci_buf, we_buf, mp_buf, spv_buf, ain_buf, aw4_buf, asum_buf);
    stackf_kernel<<<2688, 256, 0, stream>>>(v_idx, attr_emb, F2, ci_buf, we_buf, cat_mat, conn,
                                            ain_buf, asum_buf, afind_buf, atr_buf, pooled);
    c7u_kernel<<<dim3(8, 16), 256, 0, stream>>>(pooled, W_desc, partE, spv_buf, mp_buf,
                                                afind_buf, ain_buf, atr_buf, aw4_buf,
                                                att_stack, sptr_buf);
  }

  cl1_kernel<<<dim3(16, 8), 256, 0, stream>>>(partE, mp_buf, mem, outs, qlen, W_cls1, partH);
  cl2_kernel<<<dim3(1, 8), 256, 0, stream>>>(partH, b_cls1, W_cls2, partJ);
  cl3_kernel<<<7, 256, 0, stream>>>(partJ, b_cls2, logits);
}

// Round 15
// 1491.268 us; speedup vs baseline: 1.3505x; 1.3505x over previous
//
#include <hip/hip_runtime.h>
#include <math.h>

#define B 64
#define S 32
#define NN 128
#define DV 512
#define DW 300
#define DH 1024
#define CLS 1024
#define T_CTRL 12
#define LL 4
#define NA 28
#define NE 16
#define MM 6

__device__ __forceinline__ float sigmoidf_(float x) { return 1.0f / (1.0f + expf(-x)); }

// ================= double-buffered 64x64-tile GEMM core (float4-k LDS) =================
template<bool TRANS, class AF, class WF>
__device__ __forceinline__ void gemm_core(int kbeg, int Kc, AF loadA, WF loadW,
                                          float* part, int Cld, int orow) {
  __shared__ float Ast[2][64 * 36];
  __shared__ float Ws[2][32 * 64];
  const int tid = threadIdx.x;
  const int j0 = blockIdx.x * 64;
  const int ntiles = Kc >> 5;
  const int rg = tid & 15, cg = tid >> 4;
  float4 av[2], wv[2];

  auto fetch = [&](int kt) {
    #pragma unroll
    for (int i2 = 0; i2 < 2; ++i2) {
      int idx = tid + i2 * 256;
      av[i2] = loadA(idx >> 3, kt + (idx & 7) * 4);
    }
    #pragma unroll
    for (int i2 = 0; i2 < 2; ++i2) {
      int idx = tid + i2 * 256;
      if (!TRANS) wv[i2] = loadW(kt + (idx >> 4), j0 + (idx & 15) * 4);
      else        wv[i2] = loadW(j0 + (idx >> 3), kt + (idx & 7) * 4);
    }
  };
  auto commit = [&](int buf) {
    #pragma unroll
    for (int i2 = 0; i2 < 2; ++i2) {
      int idx = tid + i2 * 256;
      *(float4*)&Ast[buf][(idx >> 3) * 36 + (idx & 7) * 4] = av[i2];
    }
    #pragma unroll
    for (int i2 = 0; i2 < 2; ++i2) {
      int idx = tid + i2 * 256;
      if (!TRANS) {
        *(float4*)&Ws[buf][(idx >> 4) * 64 + (idx & 15) * 4] = wv[i2];
      } else {
        int jloc = idx >> 3, k4 = (idx & 7) * 4;
        Ws[buf][(k4 + 0) * 64 + jloc] = wv[i2].x;
        Ws[buf][(k4 + 1) * 64 + jloc] = wv[i2].y;
        Ws[buf][(k4 + 2) * 64 + jloc] = wv[i2].z;
        Ws[buf][(k4 + 3) * 64 + jloc] = wv[i2].w;
      }
    }
  };

  float acc[4][4] = {};
  fetch(kbeg);
  commit(0);
  __syncthreads();
  for (int i = 0; i < ntiles; ++i) {
    if (i + 1 < ntiles) fetch(kbeg + (i + 1) * 32);
    const float* As = &Ast[i & 1][0];
    const float* Wp = &Ws[i & 1][0];
    #pragma unroll
    for (int kq = 0; kq < 8; ++kq) {
      float4 a0 = *(const float4*)&As[(rg     ) * 36 + kq * 4];
      float4 a1 = *(const float4*)&As[(rg + 16) * 36 + kq * 4];
      float4 a2 = *(const float4*)&As[(rg + 32) * 36 + kq * 4];
      float4 a3 = *(const float4*)&As[(rg + 48) * 36 + kq * 4];
      float4 w0 = *(const float4*)&Wp[(kq * 4 + 0) * 64 + cg * 4];
      float4 w1 = *(const float4*)&Wp[(kq * 4 + 1) * 64 + cg * 4];
      float4 w2 = *(const float4*)&Wp[(kq * 4 + 2) * 64 + cg * 4];
      float4 w3 = *(const float4*)&Wp[(kq * 4 + 3) * 64 + cg * 4];
      #define STEP(m, AV) \
        acc[m][0]=fmaf(AV.x,w0.x,acc[m][0]); acc[m][1]=fmaf(AV.x,w0.y,acc[m][1]); \
        acc[m][2]=fmaf(AV.x,w0.z,acc[m][2]); acc[m][3]=fmaf(AV.x,w0.w,acc[m][3]); \
        acc[m][0]=fmaf(AV.y,w1.x,acc[m][0]); acc[m][1]=fmaf(AV.y,w1.y,acc[m][1]); \
        acc[m][2]=fmaf(AV.y,w1.z,acc[m][2]); acc[m][3]=fmaf(AV.y,w1.w,acc[m][3]); \
        acc[m][0]=fmaf(AV.z,w2.x,acc[m][0]); acc[m][1]=fmaf(AV.z,w2.y,acc[m][1]); \
        acc[m][2]=fmaf(AV.z,w2.z,acc[m][2]); acc[m][3]=fmaf(AV.z,w2.w,acc[m][3]); \
        acc[m][0]=fmaf(AV.w,w3.x,acc[m][0]); acc[m][1]=fmaf(AV.w,w3.y,acc[m][1]); \
        acc[m][2]=fmaf(AV.w,w3.z,acc[m][2]); acc[m][3]=fmaf(AV.w,w3.w,acc[m][3]);
      STEP(0, a0) STEP(1, a1) STEP(2, a2) STEP(3, a3)
      #undef STEP
    }
    if (i + 1 < ntiles) { __syncthreads(); commit((i + 1) & 1); __syncthreads(); }
  }
  float* op = part + (size_t)orow * 64 * Cld + j0 + cg * 4;
  #pragma unroll
  for (int m = 0; m < 4; ++m)
    *(float4*)&op[(size_t)(rg + 16 * m) * Cld] = make_float4(acc[m][0], acc[m][1], acc[m][2], acc[m][3]);
}

// ---------------- init ----------------
__global__ void init_kernel(float* c_lstm, float* c_ctrl, float* att_stack, float* mem, float* sptr) {
  int idx = blockIdx.x * 256 + threadIdx.x;
  if (idx < B * DH) { c_lstm[idx] = 0.f; c_ctrl[idx] = 0.f; }
  if (idx < B * NN * LL) att_stack[idx] = 0.f;
  if (idx < B * DV) mem[idx] = 0.f;
  if (idx < B * LL) sptr[idx] = ((idx & (LL - 1)) == 0) ? 1.f : 0.f;
}

// ---------------- embq: rows t*B+b, padded 300->320 ----------------
__global__ void embq_kernel(const int* __restrict__ questions, const float* __restrict__ enc_emb,
                            float* __restrict__ embq) {
  int row = blockIdx.x;
  int t = row >> 6, b = row & 63;
  int qid = questions[b * S + t];
  int c = threadIdx.x;
  embq[(size_t)row * 320 + c] = (c < DW) ? enc_emb[(size_t)qid * DW + c] : 0.f;
}

// ---------------- X = embq @ Wx for all steps (rows 2048) ----------------
__global__ __launch_bounds__(256) void xgemm_kernel(const float* __restrict__ embq,
                                                    const float* __restrict__ Wx,
                                                    float* __restrict__ X) {
  auto Al = [&](int r, int k) -> float4 {
    return *(const float4*)&embq[(size_t)(blockIdx.y * 64 + r) * 320 + k];
  };
  auto Wl = [&](int k, int j) -> float4 {
    if (k < 300) return *(const float4*)&Wx[(size_t)k * 4096 + j];
    return make_float4(0.f, 0.f, 0.f, 0.f);
  };
  gemm_core<false>(0, 320, Al, Wl, X, 4096, blockIdx.y);
}

// ---------------- F2 = attr_emb @ W_find (rows padded to 1024) ----------------
__global__ __launch_bounds__(256) void f2_kernel(const float* __restrict__ attr_emb,
                                                 const float* __restrict__ W_find,
                                                 float* __restrict__ F2) {
  auto Al = [&](int r, int k) -> float4 {
    int gr = blockIdx.y * 64 + r;
    if (gr > 999) gr = 999;
    return *(const float4*)&attr_emb[(size_t)gr * 512 + k];
  };
  auto Wl = [&](int k, int j) -> float4 { return *(const float4*)&W_find[(size_t)k * 512 + j]; };
  gemm_core<false>(0, 512, Al, Wl, F2, 512, blockIdx.y);
}

// ---------------- LSTM GEMM (per step): h_{t-1} @ Wh, split-K 8 ----------------
__global__ __launch_bounds__(256) void lstm_gemm_kernel(const float* __restrict__ h_prev,
                                                        const float* __restrict__ Wh,
                                                        float* __restrict__ part) {
  auto Al = [&](int r, int k) -> float4 { return *(const float4*)&h_prev[(size_t)r * 1024 + k]; };
  auto Wl = [&](int k, int j) -> float4 { return *(const float4*)&Wh[(size_t)k * 4096 + j]; };
  gemm_core<false>(blockIdx.y * 128, 128, Al, Wl, part, 4096, blockIdx.y);
}

// ---------------- LSTM gates: X_t + h partials + bias ----------------
__global__ __launch_bounds__(256) void lstm_gate_kernel(const float* __restrict__ part, int SK,
                                                        const float* __restrict__ X, int t,
                                                        const float* __restrict__ b_lstm,
                                                        float* __restrict__ h_out, float* __restrict__ c_st) {
  int idx = blockIdx.x * 256 + threadIdx.x;
  int b = idx >> 10, j = idx & 1023;
  const float* xr = X + ((size_t)t * 64 + b) * 4096;
  float gi = xr[j], gf = xr[1024 + j], gg = xr[2048 + j], go = xr[3072 + j];
  const float* pb = part + (size_t)b * 4096;
  for (int c = 0; c < SK; ++c) {
    const float* p = pb + (size_t)c * 262144;
    gi += p[j]; gf += p[1024 + j]; gg += p[2048 + j]; go += p[3072 + j];
  }
  gi += b_lstm[j]; gf += b_lstm[1024 + j]; gg += b_lstm[2048 + j]; go += b_lstm[3072 + j];
  float c = sigmoidf_(gf) * c_st[idx] + sigmoidf_(gi) * tanhf(gg);
  h_out[idx] = sigmoidf_(go) * tanhf(c);
  c_st[idx] = c;
}

// ---------------- C1: cq partials (+ fused mem-EPI of previous iter) ----------------
__global__ __launch_bounds__(256) void c1_kernel(const float* __restrict__ c_ctrl,
                                                 const float* __restrict__ outs, const int* __restrict__ qlen,
                                                 const float* __restrict__ W_cq, float* __restrict__ partA,
                                                 const float* __restrict__ partE, const float* __restrict__ mp,
                                                 float* __restrict__ mem, int do_epi) {
  if (blockIdx.x == 16) {
    if (!do_epi) return;
    int t0 = blockIdx.y * 256 + threadIdx.x;
    #pragma unroll
    for (int i = 0; i < 4; ++i) {
      int f4 = t0 + i * 2048;
      int b = f4 >> 7, j = (f4 & 127) * 4;
      const float* m = &mp[b * 6];
      float s04 = m[0] + m[1] + m[2] + m[3] + m[4];
      float4 s = make_float4(0.f, 0.f, 0.f, 0.f);
      for (int c = 0; c < 8; ++c) {
        float4 v = *(const float4*)&partE[(size_t)c * 32768 + b * 512 + j];
        s.x += v.x; s.y += v.y; s.z += v.z; s.w += v.w;
      }
      float4 o = *(const float4*)&mem[b * 512 + j];
      o.x = s04 * o.x + m[5] * s.x; o.y = s04 * o.y + m[5] * s.y;
      o.z = s04 * o.z + m[5] * s.z; o.w = s04 * o.w + m[5] * s.w;
      *(float4*)&mem[b * 512 + j] = o;
    }
    return;
  }
  auto Al = [&](int r, int k) -> float4 {
    if (k < 1024) return *(const float4*)&c_ctrl[r * 1024 + k];
    int tq = qlen[r] - 1;
    return *(const float4*)&outs[(size_t)tq * 65536 + r * 1024 + (k - 1024)];
  };
  auto Wl = [&](int k, int j) -> float4 { return *(const float4*)&W_cq[(size_t)k * 1024 + j]; };
  gemm_core<false>(blockIdx.y * 256, 256, Al, Wl, partA, 1024, blockIdx.y);
}

// ---------------- C2: am partials, A = tanh(reduce(partA)+b_cq) ----------------
__global__ __launch_bounds__(256) void c2_kernel(const float* __restrict__ partA,
                                                 const float* __restrict__ b_cq,
                                                 const float* __restrict__ W_att,
                                                 const float* __restrict__ W_mod,
                                                 float* __restrict__ partB) {
  auto Al = [&](int r, int k) -> float4 {
    float4 s = *(const float4*)&b_cq[k];
    for (int c = 0; c < 8; ++c) {
      float4 v = *(const float4*)&partA[(size_t)c * 65536 + r * 1024 + k];
      s.x += v.x; s.y += v.y; s.z += v.z; s.w += v.w;
    }
    return make_float4(tanhf(s.x), tanhf(s.y), tanhf(s.z), tanhf(s.w));
  };
  auto Wl = [&](int k, int j) -> float4 {
    if (j < 1024) return *(const float4*)&W_att[(size_t)k * 1024 + j];
    float v[4];
    #pragma unroll
    for (int i = 0; i < 4; ++i) {
      int jj = j + i;
      v[i] = (jj < 1030) ? W_mod[(size_t)k * 6 + (jj - 1024)] : 0.f;
    }
    return make_float4(v[0], v[1], v[2], v[3]);
  };
  gemm_core<false>(blockIdx.y * 64, 64, Al, Wl, partB, 1088, blockIdx.y);
}

// ---------------- attn: aw-reduce + al + softmax + c_ctrl (merged) ----------------
__global__ __launch_bounds__(256) void attn_kernel(const float* __restrict__ partB,
                                                   const float* __restrict__ outs,
                                                   const int* __restrict__ qlen,
                                                   float* __restrict__ c_ctrl) {
  int b = blockIdx.x >> 2, hq = blockIdx.x & 3;
  int tid = threadIdx.x;
  __shared__ float aw[DH];
  __shared__ float alv[S];
  __shared__ float cvs[S];
  {
    int c4 = tid * 4;
    float4 s = make_float4(0.f, 0.f, 0.f, 0.f);
    for (int c = 0; c < 16; ++c) {
      float4 v = *(const float4*)&partB[(size_t)c * 69632 + b * 1088 + c4];
      s.x += v.x; s.y += v.y; s.z += v.z; s.w += v.w;
    }
    *(float4*)&aw[c4] = s;
  }
  __syncthreads();
  {
    int wv = tid >> 6, lane = tid & 63;
    #pragma unroll
    for (int u = 0; u < 4; ++u) {
      int s2 = wv * 4 + u;
      const float4* orow = (const float4*)&outs[(size_t)s2 * 65536 + b * 1024];
      float pr = 0.f;
      #pragma unroll
      for (int q = 0; q < 4; ++q) {
        float4 f = orow[lane + 64 * q];
        float4 w = *(const float4*)&aw[(lane + 64 * q) * 4];
        pr += f.x * w.x + f.y * w.y + f.z * w.z + f.w * w.w;
      }
      #pragma unroll
      for (int off = 32; off > 0; off >>= 1) pr += __shfl_xor(pr, off);
      if (lane == 0) alv[s2] = pr;
    }
  }
  __syncthreads();
  if (tid < 64) {
    int len = qlen[b];
    float v = (tid < S && tid < len) ? alv[tid] : -1e9f;
    float mx = v;
    #pragma unroll
    for (int off = 32; off > 0; off >>= 1) mx = fmaxf(mx, __shfl_xor(mx, off));
    float e = (tid < S && tid < len) ? expf(v - mx) : 0.f;
    float sm = e;
    #pragma unroll
    for (int off = 32; off > 0; off >>= 1) sm += __shfl_xor(sm, off);
    if (tid < S) cvs[tid] = e / sm;
  }
  __syncthreads();
  {
    int h = hq * 256 + tid;
    float a = 0.f;
    #pragma unroll 8
    for (int s2 = 0; s2 < S; ++s2)
      a = fmaf(cvs[s2], outs[(size_t)s2 * 65536 + b * 1024 + h], a);
    c_ctrl[b * 1024 + h] = a;
  }
}

// ---------------- C4: c_i partials ----------------
__global__ __launch_bounds__(256) void c4_kernel(const float* __restrict__ c_ctrl,
                                                 const float* __restrict__ W_q,
                                                 float* __restrict__ partC) {
  auto Al = [&](int r, int k) -> float4 { return *(const float4*)&c_ctrl[r * 1024 + k]; };
  auto Wl = [&](int k, int j) -> float4 { return *(const float4*)&W_q[(size_t)k * 512 + j]; };
  gemm_core<false>(blockIdx.y * 64, 64, Al, Wl, partC, 512, blockIdx.y);
}

// ---------------- prep: c_i reduce(+relu) + we logits + softmaxes + ptrs + a_in/a_w4/asum ----------------
__global__ __launch_bounds__(256) void prep_kernel(const float* __restrict__ partC,
                                                   const float* __restrict__ partB,
                                                   const float* __restrict__ b_q,
                                                   const float* __restrict__ edge_cat,
                                                   const float* __restrict__ sptr_in,
                                                   const float* __restrict__ att_stack,
                                                   float* __restrict__ c_i, float* __restrict__ we,
                                                   float* __restrict__ mp, float* __restrict__ spv,
                                                   float* __restrict__ ain, float* __restrict__ aw4,
                                                   float* __restrict__ asum) {
  int b = blockIdx.x, tid = threadIdx.x;
  __shared__ float ci[512];
  __shared__ float lds[64];
  for (int col = tid; col < 512; col += 256) {
    float s = b_q[col];
    for (int c = 0; c < 16; ++c) s += partC[(size_t)c * 32768 + b * 512 + col];
    s = fmaxf(s, 0.f);
    ci[col] = s;
    c_i[b * 512 + col] = s;
  }
  if (tid < MM) {
    float s = 0.f;
    for (int c = 0; c < 16; ++c) s += partB[(size_t)c * 69632 + b * 1088 + 1024 + tid];
    lds[16 + tid] = s;
  }
  __syncthreads();
  {
    int wv = tid >> 6, lane = tid & 63;
    for (int e = wv; e < NE; e += 4) {
      const float* er = &edge_cat[(size_t)e * 512];
      float p = 0.f;
      #pragma unroll
      for (int q = 0; q < 8; ++q) p = fmaf(ci[lane + 64 * q], er[lane + 64 * q], p);
      #pragma unroll
      for (int off = 32; off > 0; off >>= 1) p += __shfl_xor(p, off);
      if (lane == 0) lds[e] = p;
    }
  }
  __syncthreads();
  if (tid == 0) {
    float mx = lds[0];
    for (int e = 1; e < NE; ++e) mx = fmaxf(mx, lds[e]);
    float sm = 0.f, ex[NE];
    for (int e = 0; e < NE; ++e) { ex[e] = expf(lds[e] - mx); sm += ex[e]; }
    for (int e = 0; e < NE; ++e) we[b * NE + e] = ex[e] / sm;
    float mx2 = lds[16];
    for (int m = 1; m < MM; ++m) mx2 = fmaxf(mx2, lds[16 + m]);
    float e6[MM], sm2 = 0.f;
    for (int m = 0; m < MM; ++m) { e6[m] = expf(lds[16 + m] - mx2); sm2 += e6[m]; }
    float p0 = sptr_in[b * 4 + 0], p1 = sptr_in[b * 4 + 1];
    float p2 = sptr_in[b * 4 + 2], p3 = sptr_in[b * 4 + 3];
    float sp[12];
    sp[0] = p0; sp[1] = p1; sp[2] = p2; sp[3] = p3;
    sp[4] = 0.f;      sp[5] = p0; sp[6] = p1; sp[7] = p2 + p3;
    sp[8] = p0 + p1;  sp[9] = p2; sp[10] = p3; sp[11] = 0.f;
    for (int i = 0; i < 12; ++i) { spv[b * 12 + i] = sp[i]; lds[22 + i] = sp[i]; }
    float val[MM];
    val[0] = rintf(p0 + p1 + p2 + p3);
    val[1] = rintf(p0 + p1 + p2);
    val[2] = rintf(p1 + p2 + p3);
    val[3] = val[2];
    val[4] = rintf(p2 + p3);
    val[5] = val[2];
    float mpv[MM], ssum = 0.f;
    #pragma unroll
    for (int m = 0; m < MM; ++m) { mpv[m] = (e6[m] / sm2) * val[m]; ssum += mpv[m]; }
    float inv = (ssum > 0.f) ? 1.f / ssum : 1.f;
    #pragma unroll
    for (int m = 0; m < MM; ++m) mp[b * MM + m] = mpv[m] * inv;
  }
  __syncthreads();
  if (tid < 128) {
    float4 st = *(const float4*)&att_stack[(b * NN + tid) * LL];
    float ainv = st.x * lds[22] + st.y * lds[23] + st.z * lds[24] + st.w * lds[25];
    float ap   = st.x * lds[30] + st.y * lds[31] + st.z * lds[32] + st.w * lds[33];
    ain[b * NN + tid] = ainv;
    aw4[b * NN + tid] = fminf(ap, ainv);
    float t2 = ainv;
    #pragma unroll
    for (int off = 32; off > 0; off >>= 1) t2 += __shfl_xor(t2, off);
    if ((tid & 63) == 0) lds[40 + (tid >> 6)] = t2;
  }
  __syncthreads();
  if (tid == 0) asum[b] = lds[40] + lds[41] + 1e-6f;
}

// ---------------- stackf: afind (via F2·c_i) + atrans + pooled ----------------
__global__ __launch_bounds__(256) void stackf_kernel(const int* __restrict__ v_idx,
                                                     const float* __restrict__ attr_emb,
                                                     const float* __restrict__ F2,
                                                     const float* __restrict__ c_i,
                                                     const float* __restrict__ we,
                                                     const int* __restrict__ cat_mat,
                                                     const float* __restrict__ conn,
                                                     const float* __restrict__ ain,
                                                     const float* __restrict__ asum,
                                                     float* __restrict__ afind,
                                                     float* __restrict__ atr,
                                                     float* __restrict__ pooled) {
  int job = blockIdx.x, tid = threadIdx.x;
  __shared__ float lds[192];
  if (job < 2048) {
    int gw = job * 4 + (tid >> 6);
    int b = gw >> 7, n = gw & 127, lane = tid & 63;
    int vid = v_idx[b * NN + n];
    const float4* fp = (const float4*)&F2[(size_t)vid * DV];
    const float4* up = (const float4*)&c_i[(size_t)b * DV];
    float pr = 0.f;
    #pragma unroll
    for (int q = 0; q < 2; ++q) {
      float4 f = fp[lane + 64 * q], u = up[lane + 64 * q];
      pr += f.x * u.x + f.y * u.y + f.z * u.z + f.w * u.w;
    }
    #pragma unroll
    for (int off = 32; off > 0; off >>= 1) pr += __shfl_xor(pr, off);
    if (lane == 0) afind[b * NN + n] = sigmoidf_(pr * 0.04419417382415922f);
  } else if (job < 2560) {
    int j2 = job - 2048;
    int b = j2 >> 3, ig = j2 & 7;
    if (tid < 128) lds[tid] = ain[b * NN + tid];
    else if (tid < 144) lds[tid] = we[b * NE + tid - 128];
    __syncthreads();
    int i = ig * 16 + (tid >> 4);
    const int* crow = &cat_mat[((size_t)b * NN + i) * NN];
    const float* nrow = &conn[((size_t)b * NN + i) * NN];
    float a = 0.f;
    #pragma unroll
    for (int q = 0; q < 8; ++q) {
      int j = (tid & 15) + 16 * q;
      a = fmaf(lds[128 + crow[j]] * nrow[j], lds[j], a);
    }
    a += __shfl_xor(a, 1); a += __shfl_xor(a, 2); a += __shfl_xor(a, 4); a += __shfl_xor(a, 8);
    if ((tid & 15) == 0) atr[b * NN + i] = fminf(a, 1.f);
  } else {
    int j3 = job - 2560;
    int b = j3 >> 1, d = (j3 & 1) * 256 + tid;
    int* vidL = (int*)&lds[128];
    if (tid < 128) { lds[tid] = ain[b * NN + tid]; vidL[tid] = v_idx[b * NN + tid]; }
    __syncthreads();
    float a = 0.f;
    #pragma unroll 4
    for (int n = 0; n < NN; ++n)
      a = fmaf(lds[n], attr_emb[(size_t)vidL[n] * DV + d], a);
    pooled[b * DV + d] = a / asum[b];
  }
}

// ---------------- C7 + update (merged): grid (8,16) ----------------
__global__ __launch_bounds__(256) void c7u_kernel(const float* __restrict__ pooled,
                                                  const float* __restrict__ W_desc,
                                                  float* __restrict__ partE,
                                                  const float* __restrict__ spv,
                                                  const float* __restrict__ mp,
                                                  const float* __restrict__ afind,
                                                  const float* __restrict__ ain,
                                                  const float* __restrict__ atr,
                                                  const float* __restrict__ aw4,
                                                  float* __restrict__ att_stack,
                                                  float* __restrict__ sptr) {
  int tid = threadIdx.x;
  if (blockIdx.y < 8) {
    auto Al = [&](int r, int k) -> float4 { return *(const float4*)&pooled[r * 512 + k]; };
    auto Wl = [&](int k, int j) -> float4 { return *(const float4*)&W_desc[(size_t)k * 512 + j]; };
    gemm_core<false>(blockIdx.y * 64, 64, Al, Wl, partE, 512, blockIdx.y);
    return;
  }
  int b = (blockIdx.y - 8) * 8 + blockIdx.x;
  __shared__ float sp[12], smp[MM];
  if (tid < 12) sp[tid] = spv[b * 12 + tid];
  else if (tid < 12 + MM) smp[tid - 12] = mp[b * MM + (tid - 12)];
  __syncthreads();
  #pragma unroll
  for (int i = 0; i < 2; ++i) {
    int e = tid + i * 256;
    int n = e >> 2, l = e & 3;
    float st = att_stack[(b * NN + n) * LL + l];
    float keep = smp[0] + smp[5] + smp[1] * (1.f - sp[4 + l]) + (smp[2] + smp[3]) * (1.f - sp[l])
               + smp[4] * (1.f - sp[8 + l]);
    float add = sp[4 + l] * smp[1] * afind[b * NN + n]
              + sp[l] * (smp[2] * atr[b * NN + n] + smp[3] * ain[b * NN + n] * afind[b * NN + n])
              + sp[8 + l] * smp[4] * aw4[b * NN + n];
    att_stack[(b * NN + n) * LL + l] = keep * st + add;
  }
  if (tid < LL)
    sptr[b * LL + tid] = (smp[0] + smp[2] + smp[3]) * sp[tid] + smp[1] * sp[4 + tid]
                       + (smp[4] + smp[5]) * sp[8 + tid];
}

// ---------------- CL1: h1 partials; A = [EPI(mem,partE) | outs@qlen] ----------------
__global__ __launch_bounds__(256) void cl1_kernel(const float* __restrict__ partE,
                                                  const float* __restrict__ mp,
                                                  const float* __restrict__ mem,
                                                  const float* __restrict__ outs,
                                                  const int* __restrict__ qlen,
                                                  const float* __restrict__ W_cls1,
                                                  float* __restrict__ partH) {
  auto Al = [&](int r, int k) -> float4 {
    if (k < 512) {
      float4 s = make_float4(0.f, 0.f, 0.f, 0.f);
      for (int c = 0; c < 8; ++c) {
        float4 v = *(const float4*)&partE[(size_t)c * 32768 + r * 512 + k];
        s.x += v.x; s.y += v.y; s.z += v.z; s.w += v.w;
      }
      const float* m = &mp[r * 6];
      float s04 = m[0] + m[1] + m[2] + m[3] + m[4];
      float4 o = *(const float4*)&mem[r * 512 + k];
      return make_float4(s04 * o.x + m[5] * s.x, s04 * o.y + m[5] * s.y,
                         s04 * o.z + m[5] * s.z, s04 * o.w + m[5] * s.w);
    }
    int tq = qlen[r] - 1;
    return *(const float4*)&outs[(size_t)tq * 65536 + r * 1024 + (k - 512)];
  };
  auto Wl = [&](int k, int j) -> float4 { return *(const float4*)&W_cls1[(size_t)k * 1024 + j]; };
  gemm_core<false>(blockIdx.y * 192, 192, Al, Wl, partH, 1024, blockIdx.y);
}

// ---------------- CL2: logits partials; A = relu(reduce(partH)+b_cls1) ----------------
__global__ __launch_bounds__(256) void cl2_kernel(const float* __restrict__ partH,
                                                  const float* __restrict__ b_cls1,
                                                  const float* __restrict__ W_cls2,
                                                  float* __restrict__ partJ) {
  auto Al = [&](int r, int k) -> float4 {
    float4 s = *(const float4*)&b_cls1[k];
    for (int c = 0; c < 8; ++c) {
      float4 v = *(const float4*)&partH[(size_t)c * 65536 + r * 1024 + k];
      s.x += v.x; s.y += v.y; s.z += v.z; s.w += v.w;
    }
    return make_float4(fmaxf(s.x, 0.f), fmaxf(s.y, 0.f), fmaxf(s.z, 0.f), fmaxf(s.w, 0.f));
  };
  auto Wl = [&](int k, int j) -> float4 {
    float v[4];
    #pragma unroll
    for (int i = 0; i < 4; ++i) { int jj = j + i; v[i] = (jj < NA) ? W_cls2[(size_t)k * NA + jj] : 0.f; }
    return make_float4(v[0], v[1], v[2], v[3]);
  };
  gemm_core<false>(blockIdx.y * 128, 128, Al, Wl, partJ, 64, blockIdx.y);
}

// ---------------- CL3: final logits reduce ----------------
__global__ void cl3_kernel(const float* __restrict__ partJ, const float* __restrict__ b_cls2,
                           float* __restrict__ logits) {
  int idx = blockIdx.x * 256 + threadIdx.x;
  if (idx >= B * NA) return;
  int r = idx / NA, j = idx - r * NA;
  float s = b_cls2[j];
  for (int c = 0; c < 8; ++c) s += partJ[(size_t)c * 4096 + r * 64 + j];
  logits[idx] = s;
}

extern "C" void kernel_launch(void* const* d_in, const int* in_sizes, int n_in,
                              void* d_out, int out_size, void* d_ws, size_t ws_size,
                              hipStream_t stream) {
  const int*   questions = (const int*)d_in[0];
  const int*   qlen      = (const int*)d_in[1];
  const float* conn      = (const float*)d_in[2];
  const int*   cat_mat   = (const int*)d_in[3];
  const int*   v_idx     = (const int*)d_in[4];
  const float* attr_emb  = (const float*)d_in[5];
  const float* edge_cat  = (const float*)d_in[6];
  const float* enc_emb   = (const float*)d_in[7];
  const float* Wx        = (const float*)d_in[8];
  const float* Wh        = (const float*)d_in[9];
  const float* b_lstm    = (const float*)d_in[10];
  const float* W_cq      = (const float*)d_in[11];
  const float* b_cq      = (const float*)d_in[12];
  const float* W_mod     = (const float*)d_in[13];
  const float* W_att     = (const float*)d_in[14];
  const float* W_q       = (const float*)d_in[15];
  const float* b_q       = (const float*)d_in[16];
  const float* W_find    = (const float*)d_in[17];
  const float* W_desc    = (const float*)d_in[18];
  const float* W_cls1    = (const float*)d_in[19];
  const float* b_cls1    = (const float*)d_in[20];
  const float* W_cls2    = (const float*)d_in[21];
  const float* b_cls2    = (const float*)d_in[22];
  float* logits = (float*)d_out;

  float* w = (float*)d_ws;
  size_t off = 0;
  float* outs      = w + off; off += (size_t)S * B * DH;     // 2,097,152
  float* embq      = w + off; off += (size_t)S * B * 320;    //   655,360
  float* X         = w + off; off += (size_t)S * B * 4096;   // 8,388,608
  float* F2        = w + off; off += 1024 * 512;             //   524,288
  float* share     = w + off; off += 2457600;                // partLSTM / partA / partB / partC union
  float* partE     = w + off; off += 262144;
  float* partH     = w + off; off += 524288;
  float* partJ     = w + off; off += 32768;
  float* c_ctrl    = w + off; off += B * DH;
  float* c_lstm    = w + off; off += B * DH;
  float* ci_buf    = w + off; off += B * DV;
  float* we_buf    = w + off; off += B * NE;
  float* mp_buf    = w + off; off += B * MM;
  float* spv_buf   = w + off; off += B * 12;
  float* ain_buf   = w + off; off += B * NN;
  float* aw4_buf   = w + off; off += B * NN;
  float* afind_buf = w + off; off += B * NN;
  float* atr_buf   = w + off; off += B * NN;
  float* asum_buf  = w + off; off += B;
  float* att_stack = w + off; off += B * NN * LL;
  float* sptr_buf  = w + off; off += B * LL;
  float* mem       = w + off; off += B * DV;
  float* pooled    = w + off; off += B * DV;

  float* partLSTM = share;
  float* partA = share;
  float* partB = share + 524288;
  float* partC = share + 1638400;

  init_kernel<<<256, 256, 0, stream>>>(c_lstm, c_ctrl, att_stack, mem, sptr_buf);
  embq_kernel<<<S * B, 320, 0, stream>>>(questions, enc_emb, embq);
  xgemm_kernel<<<dim3(64, 32), 256, 0, stream>>>(embq, Wx, X);
  f2_kernel<<<dim3(8, 16), 256, 0, stream>>>(attr_emb, W_find, F2);

  // t = 0: h = gate(X_0) (no h-GEMM)
  lstm_gate_kernel<<<(B * DH) / 256, 256, 0, stream>>>(partLSTM, 0, X, 0, b_lstm, outs, c_lstm);
  for (int t = 1; t < S; ++t) {
    lstm_gemm_kernel<<<dim3(64, 8), 256, 0, stream>>>(outs + (size_t)(t - 1) * B * DH, Wh, partLSTM);
    lstm_gate_kernel<<<(B * DH) / 256, 256, 0, stream>>>(partLSTM, 8, X, t, b_lstm,
                                                         outs + (size_t)t * B * DH, c_lstm);
  }

  for (int it = 0; it < T_CTRL; ++it) {
    c1_kernel<<<dim3(17, 8), 256, 0, stream>>>(c_ctrl, outs, qlen, W_cq, partA,
                                               partE, mp_buf, mem, it > 0 ? 1 : 0);
    c2_kernel<<<dim3(17, 16), 256, 0, stream>>>(partA, b_cq, W_att, W_mod, partB);
    attn_kernel<<<256, 256, 0, stream>>>(partB, outs, qlen, c_ctrl);
    c4_kernel<<<dim3(8, 16), 256, 0, stream>>>(c_ctrl, W_q, partC);
    prep_kernel<<<64, 256, 0, stream>>>(partC, partB, b_q, edge_cat, sptr_buf, att_stack,
                                        ci_buf, we_buf, mp_buf, spv_buf, ain_buf, aw4_buf, asum_buf);
    stackf_kernel<<<2688, 256, 0, stream>>>(v_idx, attr_emb, F2, ci_buf, we_buf, cat_mat, conn,
                                            ain_buf, asum_buf, afind_buf, atr_buf, pooled);
    c7u_kernel<<<dim3(8, 16), 256, 0, stream>>>(pooled, W_desc, partE, spv_buf, mp_buf,
                                                afind_buf, ain_buf, atr_buf, aw4_buf,
                                                att_stack, sptr_buf);
  }

  cl1_kernel<<<dim3(16, 8), 256, 0, stream>>>(partE, mp_buf, mem, outs, qlen, W_cls1, partH);
  cl2_kernel<<<dim3(1, 8), 256, 0, stream>>>(partH, b_cls1, W_cls2, partJ);
  cl3_kernel<<<7, 256, 0, stream>>>(partJ, b_cls2, logits);
}